// Round 3
// baseline (1112.453 us; speedup 1.0000x reference)
//
#include <hip/hip_runtime.h>

// Problem constants (from reference)
#define N_A 100000
#define N_B 60000
#define N_C 40000
#define NTOT 200000   // N_A + N_B + N_C
#define NEDGE 3200000
#define D 64

#define SCAN_BLK 1024
#define NB_SCAN ((NTOT + SCAN_BLK - 1) / SCAN_BLK)   // 196

// ---------------------------------------------------------------------------
// Register-tiled fp32 GEMM: Y[node0+n] = act(X[n] @ W + b)
//   X: [Nn][K], W: [K][64], b: [64].  Block = 256 nodes x 64 dims,
//   thread = 8n x 8d (64 acc VGPRs), k-chunk = 32.
//   sF is staged k-major (transposed) so compute reads are ds_read_b128:
//   per k: 2 b128 of W + 2 b128 of feat -> 64 FMAs (1 B/FMA).
//   LDS = 33.3 KB + 8 KB -> 3 blocks/CU.
// ---------------------------------------------------------------------------
template <int K, bool RELU>
__global__ __launch_bounds__(256) void gemm64_kernel(
    const float* __restrict__ X, const float* __restrict__ W,
    const float* __restrict__ bias, float* __restrict__ Y,
    int Nn, int node0out)
{
    __shared__ float sF[32][260];   // [k][n], pad 260 (16B-aligned rows, bank shift 4/k)
    __shared__ float sW[32 * 64];   // [k][d]

    const int tid = threadIdx.x;
    const int td  = tid & 7;         // d-group: dims td*8 .. td*8+7
    const int tn  = tid >> 3;        // n-group: nodes tn*8 .. tn*8+7
    const int d0  = td * 8;
    const int n0  = tn * 8;
    const int blockNode = blockIdx.x * 256;

    float acc[8][8] = {};   // [n][d]

    for (int k0 = 0; k0 < K; k0 += 32) {
        // stage W chunk (32x64 floats = 512 float4, linear copy)
        {
            const float4* gw = (const float4*)(W + (long long)k0 * 64);
#pragma unroll
            for (int i = 0; i < 2; ++i) {
                const int idx = i * 256 + tid;
                ((float4*)sW)[idx] = gw[idx];
            }
        }
        // stage X chunk transposed: sF[k][n]; coalesced float4 global reads
        {
            const int tk = tid & 7;       // k-quad 0..7 -> k = tk*4..tk*4+3
            const int nl = tid >> 3;      // 32 nodes per pass
#pragma unroll
            for (int p = 0; p < 8; ++p) {
                const int n  = p * 32 + nl;
                const int gn = blockNode + n;
                float4 f = make_float4(0.f, 0.f, 0.f, 0.f);
                if (gn < Nn)
                    f = *(const float4*)(X + (long long)gn * K + k0 + tk * 4);
                sF[tk * 4 + 0][n] = f.x;
                sF[tk * 4 + 1][n] = f.y;
                sF[tk * 4 + 2][n] = f.z;
                sF[tk * 4 + 3][n] = f.w;
            }
        }
        __syncthreads();

#pragma unroll 4
        for (int kk = 0; kk < 32; ++kk) {
            const float4 w0 = *(const float4*)(sW + kk * 64 + d0);
            const float4 w1 = *(const float4*)(sW + kk * 64 + d0 + 4);
            const float4 f0 = *(const float4*)(&sF[kk][n0]);
            const float4 f1 = *(const float4*)(&sF[kk][n0 + 4]);
            float wv[8] = { w0.x, w0.y, w0.z, w0.w, w1.x, w1.y, w1.z, w1.w };
            float fv[8] = { f0.x, f0.y, f0.z, f0.w, f1.x, f1.y, f1.z, f1.w };
#pragma unroll
            for (int j = 0; j < 8; ++j)
#pragma unroll
                for (int i = 0; i < 8; ++i)
                    acc[j][i] = fmaf(fv[j], wv[i], acc[j][i]);
        }
        __syncthreads();
    }

    // epilogue: bias (+ReLU) and store
    float bv[8];
    *(float4*)&bv[0] = *(const float4*)(bias + d0);
    *(float4*)&bv[4] = *(const float4*)(bias + d0 + 4);
#pragma unroll
    for (int j = 0; j < 8; ++j) {
        const int gn = blockNode + n0 + j;
        if (gn < Nn) {
            float o[8];
#pragma unroll
            for (int i = 0; i < 8; ++i) {
                o[i] = acc[j][i] + bv[i];
                if (RELU) o[i] = fmaxf(o[i], 0.f);
            }
            float* yp = Y + (long long)(node0out + gn) * 64 + d0;
            *(float4*)(yp)     = *(float4*)&o[0];
            *(float4*)(yp + 4) = *(float4*)&o[4];
        }
    }
}

// ---------------------------------------------------------------------------
// CSR build: zero -> histogram -> 3-pass exclusive scan -> cursor fill
// ---------------------------------------------------------------------------
__global__ void zero_ints(int* __restrict__ p, int n)
{
    int i = blockIdx.x * blockDim.x + threadIdx.x;
    if (i < n) p[i] = 0;
}

__global__ void hist_kernel(const int* __restrict__ edst, int* __restrict__ deg, int e)
{
    int i  = blockIdx.x * blockDim.x + threadIdx.x;
    int st = gridDim.x * blockDim.x;
    for (; i < e; i += st) atomicAdd(&deg[edst[i]], 1);
}

__global__ __launch_bounds__(SCAN_BLK) void s1_blocksums(const int* __restrict__ deg,
                                                         int* __restrict__ partials, int n)
{
    const int tid = threadIdx.x;
    const int i   = blockIdx.x * SCAN_BLK + tid;
    int v = (i < n) ? deg[i] : 0;
#pragma unroll
    for (int o = 32; o; o >>= 1) v += __shfl_xor(v, o, 64);
    __shared__ int wsum[SCAN_BLK / 64];
    if ((tid & 63) == 0) wsum[tid >> 6] = v;
    __syncthreads();
    if (tid == 0) {
        int s = 0;
#pragma unroll
        for (int w = 0; w < SCAN_BLK / 64; ++w) s += wsum[w];
        partials[blockIdx.x] = s;
    }
}

__global__ __launch_bounds__(256) void s2_scan(const int* __restrict__ partials,
                                               int* __restrict__ pscan, int np)
{
    __shared__ int arr[512];
    if (threadIdx.x < np) arr[threadIdx.x] = partials[threadIdx.x];
    __syncthreads();
    if (threadIdx.x == 0) {
        int run = 0;
        for (int i = 0; i < np; ++i) { int t = arr[i]; arr[i] = run; run += t; }
    }
    __syncthreads();
    if (threadIdx.x < np) pscan[threadIdx.x] = arr[threadIdx.x];
}

__global__ __launch_bounds__(SCAN_BLK) void s3_scan(const int* __restrict__ deg,
                                                    const int* __restrict__ pscan,
                                                    int* __restrict__ row_start,
                                                    int* __restrict__ cursor, int n)
{
    const int tid  = threadIdx.x;
    const int lane = tid & 63, wid = tid >> 6;
    const int i    = blockIdx.x * SCAN_BLK + tid;
    int v = (i < n) ? deg[i] : 0;
    int x = v;
#pragma unroll
    for (int o = 1; o < 64; o <<= 1) {
        int y = __shfl_up(x, o, 64);
        if (lane >= o) x += y;
    }
    __shared__ int wsum[SCAN_BLK / 64];
    if (lane == 63) wsum[wid] = x;
    __syncthreads();
    if (tid == 0) {
        int run = 0;
#pragma unroll
        for (int w = 0; w < SCAN_BLK / 64; ++w) { int t = wsum[w]; wsum[w] = run; run += t; }
    }
    __syncthreads();
    if (i < n) {
        const int excl = x - v + wsum[wid] + pscan[blockIdx.x];
        row_start[i] = excl;
        cursor[i]    = excl;
    }
}

__global__ void fill_kernel(const int* __restrict__ esrc, const int* __restrict__ edst,
                            const float* __restrict__ ew, int* __restrict__ cursor,
                            uint2* __restrict__ csr, int e)
{
    int i  = blockIdx.x * blockDim.x + threadIdx.x;
    int st = gridDim.x * blockDim.x;
    for (; i < e; i += st) {
        const int t   = edst[i];
        const int pos = atomicAdd(&cursor[t], 1);
        csr[pos] = make_uint2((unsigned)esrc[i], __float_as_uint(ew[i]));
    }
}

// ---------------------------------------------------------------------------
// Pull-based gather + fused L2 normalize: one 64-lane wave per dst node.
// ---------------------------------------------------------------------------
__global__ __launch_bounds__(256) void gather_norm_kernel(const float* __restrict__ support,
                                                          const uint2* __restrict__ csr,
                                                          const int* __restrict__ row_start,
                                                          const int* __restrict__ deg,
                                                          float* __restrict__ out)
{
    const int lane = threadIdx.x & 63;
    const int nid  = blockIdx.x * 4 + (threadIdx.x >> 6);
    if (nid >= NTOT) return;
    const int base = row_start[nid];
    const int dg   = deg[nid];

    float acc = 0.f;
    int i = 0;
    for (; i + 4 <= dg; i += 4) {
        const uint2 c0 = csr[base + i + 0];
        const uint2 c1 = csr[base + i + 1];
        const uint2 c2 = csr[base + i + 2];
        const uint2 c3 = csr[base + i + 3];
        const float v0 = support[(long long)c0.x * D + lane];
        const float v1 = support[(long long)c1.x * D + lane];
        const float v2 = support[(long long)c2.x * D + lane];
        const float v3 = support[(long long)c3.x * D + lane];
        acc = fmaf(v0, __uint_as_float(c0.y), acc);
        acc = fmaf(v1, __uint_as_float(c1.y), acc);
        acc = fmaf(v2, __uint_as_float(c2.y), acc);
        acc = fmaf(v3, __uint_as_float(c3.y), acc);
    }
    for (; i < dg; ++i) {
        const uint2 c = csr[base + i];
        acc = fmaf(support[(long long)c.x * D + lane], __uint_as_float(c.y), acc);
    }

    float ss = acc * acc;
#pragma unroll
    for (int o = 32; o; o >>= 1) ss += __shfl_xor(ss, o, 64);
    const float nrm = fmaxf(sqrtf(ss), 1e-12f);
    out[(long long)nid * D + lane] = acc / nrm;
}

// ---------------------------------------------------------------------------
// Fallback path: zero + atomic scatter + normalize, if ws too small
// ---------------------------------------------------------------------------
__global__ void zero_kernel(float4* __restrict__ p, long long n4)
{
    long long i  = (long long)blockIdx.x * blockDim.x + threadIdx.x;
    long long st = (long long)gridDim.x * blockDim.x;
    for (; i < n4; i += st) p[i] = float4{0.f, 0.f, 0.f, 0.f};
}

__global__ void scatter_kernel(const float* __restrict__ support,
                               const float* __restrict__ ew,
                               const int* __restrict__ esrc,
                               const int* __restrict__ edst,
                               float* __restrict__ out, int E)
{
    const int d  = threadIdx.x & 63;
    int gw       = blockIdx.x * (blockDim.x >> 6) + (threadIdx.x >> 6);
    const int nw = gridDim.x * (blockDim.x >> 6);
    for (int e = gw; e < E; e += nw) {
        const int   s  = esrc[e];
        const int   t  = edst[e];
        const float we = ew[e];
        atomicAdd(&out[(long long)t * 64 + d], support[(long long)s * 64 + d] * we);
    }
}

__global__ void normalize_kernel(float* __restrict__ out, int N)
{
    const int d   = threadIdx.x & 63;
    const int row = blockIdx.x * (blockDim.x >> 6) + (threadIdx.x >> 6);
    if (row < N) {
        const long long base = (long long)row * 64;
        float x  = out[base + d];
        float ss = x * x;
#pragma unroll
        for (int o = 32; o; o >>= 1) ss += __shfl_xor(ss, o, 64);
        const float nrm = fmaxf(sqrtf(ss), 1e-12f);
        out[base + d] = x / nrm;
    }
}

extern "C" void kernel_launch(void* const* d_in, const int* in_sizes, int n_in,
                              void* d_out, int out_size, void* d_ws, size_t ws_size,
                              hipStream_t stream)
{
    const float* feat_a = (const float*)d_in[0];
    const float* W_a    = (const float*)d_in[1];
    const float* b_a    = (const float*)d_in[2];
    const float* feat_b = (const float*)d_in[3];
    const float* W_b    = (const float*)d_in[4];
    const float* b_b    = (const float*)d_in[5];
    const float* feat_c = (const float*)d_in[6];
    const float* W_c    = (const float*)d_in[7];
    const float* b_c    = (const float*)d_in[8];
    const float* gcn_W  = (const float*)d_in[9];
    const float* gcn_b  = (const float*)d_in[10];
    const float* ew     = (const float*)d_in[11];
    const int*   esrc   = (const int*)d_in[12];
    const int*   edst   = (const int*)d_in[13];

    float* out = (float*)d_out;

    // workspace layout
    char* ws = (char*)d_ws;
    const size_t off_support = 0;                               // 51,200,000 B
    const size_t off_deg     = off_support + (size_t)NTOT * D * 4;
    const size_t off_rowst   = off_deg   + (size_t)NTOT * 4;
    const size_t off_cursor  = off_rowst + (size_t)NTOT * 4;
    const size_t off_part    = off_cursor + (size_t)NTOT * 4;
    const size_t off_pscan   = off_part  + 1024;
    const size_t off_csr     = off_pscan + 1024;
    const size_t need        = off_csr + (size_t)NEDGE * 8;     // ~79.2 MB

    float* support = (float*)(ws + off_support);

    // enc = relu(feat @ W + b) written into d_out (dead after gcn reads it,
    // overwritten later by gather_norm). Then support = enc @ gcn_W + gcn_b.
    gemm64_kernel<512, true ><<<(N_A  + 255) / 256, 256, 0, stream>>>(feat_a, W_a, b_a, out, N_A, 0);
    gemm64_kernel<256, true ><<<(N_B  + 255) / 256, 256, 0, stream>>>(feat_b, W_b, b_b, out, N_B, N_A);
    gemm64_kernel<128, true ><<<(N_C  + 255) / 256, 256, 0, stream>>>(feat_c, W_c, b_c, out, N_C, N_A + N_B);
    gemm64_kernel< 64, false><<<(NTOT + 255) / 256, 256, 0, stream>>>(out, gcn_W, gcn_b, support, NTOT, 0);

    if (ws_size >= need) {
        int*   deg     = (int*)(ws + off_deg);
        int*   rowst   = (int*)(ws + off_rowst);
        int*   cursor  = (int*)(ws + off_cursor);
        int*   part    = (int*)(ws + off_part);
        int*   pscan   = (int*)(ws + off_pscan);
        uint2* csr     = (uint2*)(ws + off_csr);

        zero_ints<<<(NTOT + 255) / 256, 256, 0, stream>>>(deg, NTOT);
        hist_kernel<<<4096, 256, 0, stream>>>(edst, deg, NEDGE);
        s1_blocksums<<<NB_SCAN, SCAN_BLK, 0, stream>>>(deg, part, NTOT);
        s2_scan<<<1, 256, 0, stream>>>(part, pscan, NB_SCAN);
        s3_scan<<<NB_SCAN, SCAN_BLK, 0, stream>>>(deg, pscan, rowst, cursor, NTOT);
        fill_kernel<<<4096, 256, 0, stream>>>(esrc, edst, ew, cursor, csr, NEDGE);

        gather_norm_kernel<<<(NTOT + 3) / 4, 256, 0, stream>>>(support, csr, rowst, deg, out);
    } else {
        zero_kernel<<<2048, 256, 0, stream>>>((float4*)out, (long long)NTOT * D / 4);
        scatter_kernel<<<8192, 256, 0, stream>>>(support, ew, esrc, edst, out, NEDGE);
        normalize_kernel<<<NTOT / 4, 256, 0, stream>>>(out, NTOT);
    }
}